// Round 3
// baseline (95.552 us; speedup 1.0000x reference)
//
#include <hip/hip_runtime.h>
#include <hip/hip_bf16.h>

#define NTHREADS 256
#define N_ATOMS 1024
#define HIDDEN 64

__device__ __forceinline__ float rdlane(float v, int l) {
    return __int_as_float(__builtin_amdgcn_readlane(__float_as_int(v), l));
}

// One WAVE per atom (4 atoms per 256-thread block). Zero LDS, zero barriers.
//  - 16 ballot sweeps over the 1024 neighbors; survivors (~65) keep
//    (d, cutv signed by species) in registers.
//  - drain the 64-bit survivor mask 4 pairs/iteration: scalar ctz + uniform
//    v_readlane broadcasts; lane = (pair-slot p = lane>>4, rbf r = lane&15),
//    each lane computes ONE exp per iteration and feeds both species
//    accumulators (exp is species-independent).
//  - reduce across the 4 slots with 2 shfl_xor; lane r (0..15) holds
//    env[r][0] / env[r][1].
//  - MLP 34->64->64->64 on ALL 64 lanes: activations live in registers,
//    broadcast per-k via readlane with literal lane index; weight reads
//    coalesced (64 consecutive floats, L1-resident after first block).
__global__ __launch_bounds__(NTHREADS) void LocalFeatureEncoder_40063454937486_kernel(
    const float* __restrict__ pos,    // [B,N,3]
    const int*   __restrict__ types,  // [B,N]
    const float* __restrict__ W1,     // [34,64]
    const float* __restrict__ b1,     // [64]
    const float* __restrict__ W2,     // [64,64]
    const float* __restrict__ b2,     // [64]
    const float* __restrict__ W3,     // [64,64]
    const float* __restrict__ b3,     // [64]
    float*       __restrict__ out)    // [B,N,64]
{
    const int tid  = threadIdx.x;
    const int lane = tid & 63;
    const int a    = blockIdx.x * 4 + (tid >> 6);   // global atom b*N+i
    const int bidx = a >> 10;                       // N = 1024
    const int i    = a & (N_ATOMS - 1);

    const float* posb = pos + (size_t)bidx * N_ATOMS * 3;
    const int*   typb = types + (size_t)bidx * N_ATOMS;

    const float xi = posb[i * 3 + 0];
    const float yi = posb[i * 3 + 1];
    const float zi = posb[i * 3 + 2];

    const int   r16 = lane & 15;                    // rbf index this lane owns
    const int   slot = lane >> 4;                   // pair slot 0..3
    const float c    = (float)r16 * (2.5f / 15.0f); // rbf center

    float acc0 = 0.0f;                              // env[r][0]
    float acc1 = 0.0f;                              // env[r][1]

#pragma unroll
    for (int sweep = 0; sweep < N_ATOMS / 64; ++sweep) {
        const int j = lane + sweep * 64;
        const float px = posb[j * 3 + 0];
        const float py = posb[j * 3 + 1];
        const float pz = posb[j * 3 + 2];
        const int   tj = typb[j];
        const float dx = xi - px, dy = yi - py, dz = zi - pz;
        const float sq = dx * dx + dy * dy + dz * dz;
        const bool  pred = (j != i) && (sq < 6.25f);

        float dv = 0.0f, mp = 0.0f;                 // (d, cutv signed by species)
        if (pred) {
            const float d  = sqrtf(sq);
            const float x  = d * 0.4f;
            const float x3 = x * x * x;
            const float cutv = 1.0f + x3 * (-10.0f + x * (15.0f - 6.0f * x));
            dv = d;
            mp = (tj == 0) ? cutv : -cutv;
        }

        unsigned long long mask = __ballot(pred);
        while (mask) {
            // pop up to 4 survivors; missing slots get m=0 (contribute nothing)
            float dA = 0.0f, mA = 0.0f, dB = 0.0f, mB = 0.0f;
            float dC = 0.0f, mC = 0.0f, dD = 0.0f, mD = 0.0f;
            {
                const int s = __builtin_ctzll(mask); mask &= mask - 1;
                dA = rdlane(dv, s); mA = rdlane(mp, s);
            }
            if (mask) {
                const int s = __builtin_ctzll(mask); mask &= mask - 1;
                dB = rdlane(dv, s); mB = rdlane(mp, s);
            }
            if (mask) {
                const int s = __builtin_ctzll(mask); mask &= mask - 1;
                dC = rdlane(dv, s); mC = rdlane(mp, s);
            }
            if (mask) {
                const int s = __builtin_ctzll(mask); mask &= mask - 1;
                dD = rdlane(dv, s); mD = rdlane(mp, s);
            }
            const float d = (slot == 0) ? dA : (slot == 1) ? dB : (slot == 2) ? dC : dD;
            const float m = (slot == 0) ? mA : (slot == 1) ? mB : (slot == 2) ? mC : dD == dD ? mD : mD;
            const float diff = d - c;
            const float e = __expf(diff * diff * -36.0f);   // 1/w^2 = 36
            acc0 += e * fmaxf(m, 0.0f);
            acc1 += e * fmaxf(-m, 0.0f);
        }
    }

    // combine the 4 pair slots: lanes r, r+16, r+32, r+48 hold partial env[r]
    acc0 += __shfl_xor(acc0, 16, 64);
    acc0 += __shfl_xor(acc0, 32, 64);
    acc1 += __shfl_xor(acc1, 16, 64);
    acc1 += __shfl_xor(acc1, 32, 64);
    // now lane r (0..15) holds full env[r][0] in acc0, env[r][1] in acc1

    const int t  = lane;                            // MLP unit this lane owns
    const int ti = typb[i];                         // wave-uniform

    // ----- layer 1: 34 -> 64, SiLU.  onehot dot W1 rows 0..1 = W1[ti][t] -----
    float h1 = b1[t] + W1[ti * HIDDEN + t];
#pragma unroll
    for (int r = 0; r < 16; ++r) {
        h1 += rdlane(acc0, r) * W1[(2 + 2 * r + 0) * HIDDEN + t];
        h1 += rdlane(acc1, r) * W1[(2 + 2 * r + 1) * HIDDEN + t];
    }
    h1 = h1 / (1.0f + __expf(-h1));

    // ----- layer 2: 64 -> 64, SiLU -----
    float h2 = b2[t];
#pragma unroll
    for (int k = 0; k < HIDDEN; ++k) {
        h2 += rdlane(h1, k) * W2[k * HIDDEN + t];
    }
    h2 = h2 / (1.0f + __expf(-h2));

    // ----- layer 3: 64 -> 64, linear -----
    float o = b3[t];
#pragma unroll
    for (int k = 0; k < HIDDEN; ++k) {
        o += rdlane(h2, k) * W3[k * HIDDEN + t];
    }
    out[(size_t)a * HIDDEN + t] = o;
}

extern "C" void kernel_launch(void* const* d_in, const int* in_sizes, int n_in,
                              void* d_out, int out_size, void* d_ws, size_t ws_size,
                              hipStream_t stream) {
    const float* pos   = (const float*)d_in[0];
    const int*   types = (const int*)d_in[1];
    const float* W1    = (const float*)d_in[2];
    const float* b1    = (const float*)d_in[3];
    const float* W2    = (const float*)d_in[4];
    const float* b2    = (const float*)d_in[5];
    const float* W3    = (const float*)d_in[6];
    const float* b3    = (const float*)d_in[7];
    float*       out   = (float*)d_out;

    const int BN = in_sizes[1];                     // B*N = 8192

    LocalFeatureEncoder_40063454937486_kernel<<<BN / 4, NTHREADS, 0, stream>>>(
        pos, types, W1, b1, W2, b2, W3, b3, out);
}